// Round 1
// baseline (371.134 us; speedup 1.0000x reference)
//
#include <hip/hip_runtime.h>
#include <hip/hip_bf16.h>

#define B_ 2
#define S_ 2048
#define DM_ 1024
#define H_ 16
#define HD_ 64

using bf16x8 = __attribute__((ext_vector_type(8))) short;
using f32x4  = __attribute__((ext_vector_type(4))) float;

// XOR swizzle for [*][64]-bf16 tiles (128B row stride): spreads the 16B slot
// across banks; identical formula on write and read (G4 / T2).
__device__ __forceinline__ int swz128(int row, int bytecol) {
    return row * 128 + (bytecol ^ ((row & 7) << 4));
}

// exact-erf via Abramowitz-Stegun 7.1.26 (|err| <= 1.5e-7), no libm erff.
__device__ __forceinline__ float gelu_exact(float x) {
    float z  = x * 0.70710678118f;
    float az = fabsf(z);
    float t  = 1.0f / fmaf(0.3275911f, az, 1.0f);
    float p  = fmaf(1.061405429f, t, -1.453152027f);
    p = fmaf(p, t, 1.421413741f);
    p = fmaf(p, t, -0.284496736f);
    p = fmaf(p, t, 0.254829592f);
    p = p * t;
    float e = __expf(-az * az);
    float r = 1.0f - p * e;
    float erfv = copysignf(r, z);
    return 0.5f * x * (1.0f + erfv);
}

// ---------------- f32 -> bf16 cast ----------------
__global__ __launch_bounds__(256) void cast_bf16_kernel(const float* __restrict__ in,
                                                        __hip_bfloat16* __restrict__ out, int n) {
    int i = (blockIdx.x * 256 + threadIdx.x) * 4;
    if (i >= n) return;
    float4 v = *(const float4*)(in + i);
    __hip_bfloat16 b0 = __float2bfloat16(v.x), b1 = __float2bfloat16(v.y),
                   b2 = __float2bfloat16(v.z), b3 = __float2bfloat16(v.w);
    ushort4 o = { *(ushort*)&b0, *(ushort*)&b1, *(ushort*)&b2, *(ushort*)&b3 };
    *(ushort4*)(out + i) = o;
}

// ---------------- NT bf16 GEMM: C[M,N] = A[M,K] * Bw[N,K]^T + bias ----------------
// 128x128 tile, BK=64, 256 thr = 4 waves (2x2), 16x16x32 MFMA, swizzled LDS.
__global__ __launch_bounds__(256, 2) void gemm_nt_kernel(
    const __hip_bfloat16* __restrict__ A, const __hip_bfloat16* __restrict__ Bw,
    const float* __restrict__ bias, float* __restrict__ Cf,
    __hip_bfloat16* __restrict__ Cb, int M, int N, int K)
{
    __shared__ __align__(16) char smem[32768];  // [0,16K)=A tile, [16K,32K)=B tile
    const int tid = threadIdx.x;
    const int w = tid >> 6, lane = tid & 63, hi = lane >> 4, lo = lane & 15;
    const int wr = w >> 1, wc = w & 1;
    const int m0 = blockIdx.y * 128, n0 = blockIdx.x * 128;

    f32x4 acc[4][4];
#pragma unroll
    for (int m = 0; m < 4; ++m)
#pragma unroll
        for (int n = 0; n < 4; ++n) acc[m][n] = (f32x4){0.f, 0.f, 0.f, 0.f};

    for (int k0 = 0; k0 < K; k0 += 64) {
#pragma unroll
        for (int c = tid; c < 2048; c += 256) {
            int t = c >> 10, idx = c & 1023, row = idx >> 3, cg = idx & 7;
            const __hip_bfloat16* src = t ? (Bw + (size_t)(n0 + row) * K + (k0 + cg * 8))
                                          : (A  + (size_t)(m0 + row) * K + (k0 + cg * 8));
            float4 v = *(const float4*)src;
            *(float4*)(smem + t * 16384 + swz128(row, cg * 16)) = v;
        }
        __syncthreads();
#pragma unroll
        for (int ks = 0; ks < 2; ++ks) {
            bf16x8 af[4], bfr[4];
#pragma unroll
            for (int m = 0; m < 4; ++m)
                af[m] = *(const bf16x8*)(smem + swz128(wr * 64 + m * 16 + lo, ks * 64 + hi * 16));
#pragma unroll
            for (int n = 0; n < 4; ++n)
                bfr[n] = *(const bf16x8*)(smem + 16384 + swz128(wc * 64 + n * 16 + lo, ks * 64 + hi * 16));
#pragma unroll
            for (int m = 0; m < 4; ++m)
#pragma unroll
                for (int n = 0; n < 4; ++n)
                    acc[m][n] = __builtin_amdgcn_mfma_f32_16x16x32_bf16(af[m], bfr[n], acc[m][n], 0, 0, 0);
        }
        __syncthreads();
    }

#pragma unroll
    for (int n = 0; n < 4; ++n) {
        int gc = n0 + wc * 64 + n * 16 + lo;
        float bz = bias[gc];
#pragma unroll
        for (int m = 0; m < 4; ++m) {
            int gr = m0 + wr * 64 + m * 16 + hi * 4;
#pragma unroll
            for (int r = 0; r < 4; ++r) {
                float v = acc[m][n][r] + bz;
                size_t o = (size_t)(gr + r) * N + gc;
                if (Cf) Cf[o] = v;
                if (Cb) Cb[o] = __float2bfloat16(v);
            }
        }
    }
}

// ---------------- V[B,S,H,HD] -> Vt[B,H,HD,S] ----------------
__global__ __launch_bounds__(256) void transpose_v_kernel(const __hip_bfloat16* __restrict__ V,
                                                          __hip_bfloat16* __restrict__ Vt) {
    __shared__ __align__(16) ushort tile[64][80];  // pad to 160B stride (16B-aligned rows)
    const int tid = threadIdx.x;
    const int nt = S_ / 64;
    const int blk = blockIdx.x;
    const int t0 = (blk % nt) * 64;
    const int bh = blk / nt;
    const int h = bh % H_, b = bh / H_;
#pragma unroll
    for (int c = tid; c < 512; c += 256) {
        int row = c >> 3, cg = c & 7;
        float4 v = *(const float4*)(V + (size_t)(b * S_ + t0 + row) * DM_ + h * HD_ + cg * 8);
        *(float4*)(&tile[row][cg * 8]) = v;
    }
    __syncthreads();
#pragma unroll
    for (int c = tid; c < 512; c += 256) {
        int d = c >> 3, tg = c & 7;
        union { ushort u[8]; float4 v; } tmp;
#pragma unroll
        for (int j = 0; j < 8; ++j) tmp.u[j] = tile[tg * 8 + j][d];
        *(float4*)(Vt + ((size_t)(b * H_ + h) * HD_ + d) * S_ + t0 + tg * 8) = tmp.v;
    }
}

// ---------------- fused attention: ctx = (gelu(QK^T*scale)*hw) @ V ----------------
// block: one (b,h) x 64 q-rows; 4 waves x 16 rows. K-dim = HD = 64 (Q frags in regs).
__global__ __launch_bounds__(256, 2) void attn_kernel(
    const __hip_bfloat16* __restrict__ Q, const __hip_bfloat16* __restrict__ K,
    const __hip_bfloat16* __restrict__ Vt, __hip_bfloat16* __restrict__ ctx,
    const float* __restrict__ aw)
{
    __shared__ __align__(16) char k_lds[8192];
    __shared__ __align__(16) char v_lds[8192];
    __shared__ __align__(16) char p_lds[4][2048];  // per-wave 16x64 bf16

    const int tid = threadIdx.x;
    const int w = tid >> 6, lane = tid & 63, hi = lane >> 4, lo = lane & 15;
    const int nq = S_ / 64;
    const int blk = blockIdx.x;
    const int q0 = (blk % nq) * 64;
    const int bh = blk / nq;
    const int h = bh % H_, b = bh / H_;

    // head_w = softmax(attention_weights)[h]
    float mx = aw[0];
    for (int i = 1; i < H_; ++i) mx = fmaxf(mx, aw[i]);
    float sm = 0.f;
    for (int i = 0; i < H_; ++i) sm += expf(aw[i] - mx);
    const float hw = expf(aw[h] - mx) / sm;

    // Q fragments (A-operand): lane holds Q[q0+w*16+lo][ks*32+hi*8 .. +8]
    bf16x8 aq[2];
    {
        const __hip_bfloat16* qrow = Q + ((size_t)(b * S_ + q0 + w * 16 + lo) * DM_ + h * HD_);
        aq[0] = *(const bf16x8*)(qrow + hi * 8);
        aq[1] = *(const bf16x8*)(qrow + 32 + hi * 8);
    }

    f32x4 cacc[4];
#pragma unroll
    for (int n = 0; n < 4; ++n) cacc[n] = (f32x4){0.f, 0.f, 0.f, 0.f};

    for (int t0 = 0; t0 < S_; t0 += 64) {
#pragma unroll
        for (int c = tid; c < 1024; c += 256) {
            int t = c >> 9, idx = c & 511, row = idx >> 3, cg = idx & 7;
            const __hip_bfloat16* src = t
                ? (Vt + ((size_t)(b * H_ + h) * HD_ + row) * S_ + t0 + cg * 8)
                : (K  + (size_t)(b * S_ + t0 + row) * DM_ + h * HD_ + cg * 8);
            float4 v = *(const float4*)src;
            *(float4*)((t ? v_lds : k_lds) + swz128(row, cg * 16)) = v;
        }
        __syncthreads();

        // S = Q K^T   (16 q-rows x 64 t per wave)
        f32x4 sacc[4];
#pragma unroll
        for (int n = 0; n < 4; ++n) sacc[n] = (f32x4){0.f, 0.f, 0.f, 0.f};
#pragma unroll
        for (int ks = 0; ks < 2; ++ks) {
#pragma unroll
            for (int n = 0; n < 4; ++n) {
                bf16x8 bk = *(const bf16x8*)(k_lds + swz128(n * 16 + lo, ks * 64 + hi * 16));
                sacc[n] = __builtin_amdgcn_mfma_f32_16x16x32_bf16(aq[ks], bk, sacc[n], 0, 0, 0);
            }
        }
        // P = gelu(S*scale)*hw -> wave-private LDS (C/D layout -> A layout round trip)
#pragma unroll
        for (int n = 0; n < 4; ++n)
#pragma unroll
            for (int r = 0; r < 4; ++r) {
                float s = sacc[n][r] * 0.125f;
                float p = gelu_exact(s) * hw;
                *(__hip_bfloat16*)(p_lds[w] + swz128(hi * 4 + r, (n * 16 + lo) * 2)) =
                    __float2bfloat16(p);
            }
        // ctx += P @ V  (K-dim = t, Vt rows are d)
#pragma unroll
        for (int ks = 0; ks < 2; ++ks) {
            bf16x8 pa = *(const bf16x8*)(p_lds[w] + swz128(lo, ks * 64 + hi * 16));
#pragma unroll
            for (int n = 0; n < 4; ++n) {
                bf16x8 bv = *(const bf16x8*)(v_lds + swz128(n * 16 + lo, ks * 64 + hi * 16));
                cacc[n] = __builtin_amdgcn_mfma_f32_16x16x32_bf16(pa, bv, cacc[n], 0, 0, 0);
            }
        }
        __syncthreads();
    }

#pragma unroll
    for (int n = 0; n < 4; ++n)
#pragma unroll
        for (int r = 0; r < 4; ++r) {
            int srow = q0 + w * 16 + hi * 4 + r;
            int d = n * 16 + lo;
            ctx[(size_t)(b * S_ + srow) * DM_ + h * HD_ + d] = __float2bfloat16(cacc[n][r]);
        }
}

// ---------------- gate mix + residual + LayerNorm ----------------
__global__ __launch_bounds__(256) void epilogue_ln_kernel(
    const float* __restrict__ outp, const float* __restrict__ gpre,
    const float* __restrict__ x, const float* __restrict__ gamma,
    const float* __restrict__ beta, float* __restrict__ y)
{
    const int row = blockIdx.x, tid = threadIdx.x;
    const size_t base = (size_t)row * DM_ + tid * 4;
    float4 ov = *(const float4*)(outp + base);
    float4 gv = *(const float4*)(gpre + base);
    float4 xv = *(const float4*)(x + base);
    float yv[4];
    float s = 0.f, s2 = 0.f;
#pragma unroll
    for (int j = 0; j < 4; ++j) {
        float o = ((float*)&ov)[j], g = ((float*)&gv)[j], xx = ((float*)&xv)[j];
        float gate = 1.f / (1.f + __expf(-g));
        float yy = gate * o + (1.f - gate) * xx + xx;
        yv[j] = yy;
        s += yy; s2 += yy * yy;
    }
    const int w = tid >> 6, lane = tid & 63;
#pragma unroll
    for (int off = 32; off > 0; off >>= 1) {
        s  += __shfl_down(s, off, 64);
        s2 += __shfl_down(s2, off, 64);
    }
    __shared__ float red[8];
    if (lane == 0) { red[w] = s; red[4 + w] = s2; }
    __syncthreads();
    s  = red[0] + red[1] + red[2] + red[3];
    s2 = red[4] + red[5] + red[6] + red[7];
    const float mu = s * (1.f / DM_);
    const float var = s2 * (1.f / DM_) - mu * mu;
    const float rstd = rsqrtf(var + 1e-5f);
    float4 outv;
#pragma unroll
    for (int j = 0; j < 4; ++j) {
        int col = tid * 4 + j;
        ((float*)&outv)[j] = (yv[j] - mu) * rstd * gamma[col] + beta[col];
    }
    *(float4*)(y + base) = outv;
}

extern "C" void kernel_launch(void* const* d_in, const int* in_sizes, int n_in,
                              void* d_out, int out_size, void* d_ws, size_t ws_size,
                              hipStream_t stream) {
    const float* x  = (const float*)d_in[0];
    const float* Wq = (const float*)d_in[1];
    const float* bq = (const float*)d_in[2];
    const float* Wk = (const float*)d_in[3];
    const float* bk = (const float*)d_in[4];
    const float* Wv = (const float*)d_in[5];
    const float* bv = (const float*)d_in[6];
    const float* Wo = (const float*)d_in[7];
    const float* bo = (const float*)d_in[8];
    const float* Wg = (const float*)d_in[9];
    const float* bg = (const float*)d_in[10];
    const float* aw = (const float*)d_in[11];
    const float* gamma = (const float*)d_in[12];
    const float* beta  = (const float*)d_in[13];

    char* ws = (char*)d_ws;
    size_t off = 0;
    auto alloc = [&](size_t bytes) -> char* {
        char* p = ws + off;
        off += (bytes + 255) & ~(size_t)255;
        return p;
    };
    const size_t NTOK = (size_t)B_ * S_;   // 4096
    const size_t NELT = NTOK * DM_;        // 4194304

    __hip_bfloat16* xb   = (__hip_bfloat16*)alloc(NELT * 2);
    __hip_bfloat16* Wqb  = (__hip_bfloat16*)alloc((size_t)DM_ * DM_ * 2);
    __hip_bfloat16* Wkb  = (__hip_bfloat16*)alloc((size_t)DM_ * DM_ * 2);
    __hip_bfloat16* Wvb  = (__hip_bfloat16*)alloc((size_t)DM_ * DM_ * 2);
    __hip_bfloat16* Wob  = (__hip_bfloat16*)alloc((size_t)DM_ * DM_ * 2);
    __hip_bfloat16* Wgb  = (__hip_bfloat16*)alloc((size_t)DM_ * DM_ * 2);
    __hip_bfloat16* Qb   = (__hip_bfloat16*)alloc(NELT * 2);
    __hip_bfloat16* Kb   = (__hip_bfloat16*)alloc(NELT * 2);
    __hip_bfloat16* Vb   = (__hip_bfloat16*)alloc(NELT * 2);
    __hip_bfloat16* Vtb  = (__hip_bfloat16*)alloc(NELT * 2);
    __hip_bfloat16* ctxb = (__hip_bfloat16*)alloc(NELT * 2);
    float*          outf = (float*)alloc(NELT * 4);
    __hip_bfloat16* outb = (__hip_bfloat16*)alloc(NELT * 2);
    float*          gpre = (float*)alloc(NELT * 4);

    // casts
    cast_bf16_kernel<<<(int)(NELT / 1024), 256, 0, stream>>>(x, xb, (int)NELT);
    cast_bf16_kernel<<<1024, 256, 0, stream>>>(Wq, Wqb, DM_ * DM_);
    cast_bf16_kernel<<<1024, 256, 0, stream>>>(Wk, Wkb, DM_ * DM_);
    cast_bf16_kernel<<<1024, 256, 0, stream>>>(Wv, Wvb, DM_ * DM_);
    cast_bf16_kernel<<<1024, 256, 0, stream>>>(Wo, Wob, DM_ * DM_);
    cast_bf16_kernel<<<1024, 256, 0, stream>>>(Wg, Wgb, DM_ * DM_);

    dim3 gproj(DM_ / 128, (int)(NTOK / 128));  // (8, 32)
    gemm_nt_kernel<<<gproj, 256, 0, stream>>>(xb, Wqb, bq, nullptr, Qb, (int)NTOK, DM_, DM_);
    gemm_nt_kernel<<<gproj, 256, 0, stream>>>(xb, Wkb, bk, nullptr, Kb, (int)NTOK, DM_, DM_);
    gemm_nt_kernel<<<gproj, 256, 0, stream>>>(xb, Wvb, bv, nullptr, Vb, (int)NTOK, DM_, DM_);

    transpose_v_kernel<<<B_ * H_ * (S_ / 64), 256, 0, stream>>>(Vb, Vtb);
    attn_kernel<<<B_ * H_ * (S_ / 64), 256, 0, stream>>>(Qb, Kb, Vtb, ctxb, aw);

    gemm_nt_kernel<<<gproj, 256, 0, stream>>>(ctxb, Wob, bo, outf, outb, (int)NTOK, DM_, DM_);
    gemm_nt_kernel<<<gproj, 256, 0, stream>>>(outb, Wgb, bg, gpre, nullptr, (int)NTOK, DM_, DM_);

    epilogue_ln_kernel<<<(int)NTOK, 256, 0, stream>>>(outf, gpre, x, gamma, beta, (float*)d_out);
}

// Round 2
// 245.982 us; speedup vs baseline: 1.5088x; 1.5088x over previous
//
#include <hip/hip_runtime.h>
#include <hip/hip_bf16.h>

#define B_ 2
#define S_ 2048
#define DM_ 1024
#define H_ 16
#define HD_ 64
#define QKVLD 3072

using bf16x8 = __attribute__((ext_vector_type(8))) short;
using f32x4  = __attribute__((ext_vector_type(4))) float;

// XOR swizzle for [*][64]-bf16 tiles (128B row stride); same formula write+read.
__device__ __forceinline__ int swz128(int row, int bytecol) {
    return row * 128 + (bytecol ^ ((row & 7) << 4));
}

// tanh-form GELU: x*(1-rcp(exp2(x*(c0+c1*x^2))+1)); max err vs exact-erf ~2e-4.
__device__ __forceinline__ float gelu_fast(float x) {
    float t = x * fmaf(x * x, 0.1029451f, 2.3022082f);  // 2*0.7978846*log2e, 2*0.0356774*log2e
    float e = __builtin_amdgcn_exp2f(t);
    float r = __builtin_amdgcn_rcpf(e + 1.0f);
    return x * (1.0f - r);
}

// RNE f32->bf16 (finite inputs only): 3 VALU ops.
__device__ __forceinline__ ushort bf16_rne(float f) {
    uint b = __builtin_bit_cast(uint, f);
    b += 0x7FFF + ((b >> 16) & 1);
    return (ushort)(b >> 16);
}

// ---------------- f32 -> bf16 cast with scale ----------------
__global__ __launch_bounds__(256) void cast_bf16_kernel(const float* __restrict__ in,
                                                        __hip_bfloat16* __restrict__ out,
                                                        int n, float scale) {
    int i = (blockIdx.x * 256 + threadIdx.x) * 4;
    if (i >= n) return;
    float4 v = *(const float4*)(in + i);
    ushort4 o = { bf16_rne(v.x * scale), bf16_rne(v.y * scale),
                  bf16_rne(v.z * scale), bf16_rne(v.w * scale) };
    *(ushort4*)(out + i) = o;
}

// concat + pre-scale biases for fused QKV GEMM
__global__ __launch_bounds__(256) void concat_bias_kernel(const float* __restrict__ bq,
                                                          const float* __restrict__ bk,
                                                          const float* __restrict__ bv,
                                                          float* __restrict__ out) {
    int i = blockIdx.x * 256 + threadIdx.x;
    if (i >= 3 * DM_) return;
    float v = (i < DM_) ? bq[i] * 0.125f
                        : (i < 2 * DM_ ? bk[i - DM_] : bv[i - 2 * DM_]);
    out[i] = v;
}

// ---------------- NT bf16 GEMM: C[M,N] = A[M,K] * Bw[N,K]^T + bias ----------------
__global__ __launch_bounds__(256, 2) void gemm_nt_kernel(
    const __hip_bfloat16* __restrict__ A, int lda,
    const __hip_bfloat16* __restrict__ Bw, int ldb,
    const float* __restrict__ bias, float* __restrict__ Cf,
    __hip_bfloat16* __restrict__ Cb, int ldc, int M, int N, int K)
{
    __shared__ __align__(16) char smem[32768];
    const int tid = threadIdx.x;
    const int w = tid >> 6, lane = tid & 63, hi = lane >> 4, lo = lane & 15;
    const int wr = w >> 1, wc = w & 1;
    const int m0 = blockIdx.y * 128, n0 = blockIdx.x * 128;

    f32x4 acc[4][4];
#pragma unroll
    for (int m = 0; m < 4; ++m)
#pragma unroll
        for (int n = 0; n < 4; ++n) acc[m][n] = (f32x4){0.f, 0.f, 0.f, 0.f};

    for (int k0 = 0; k0 < K; k0 += 64) {
#pragma unroll
        for (int c = tid; c < 2048; c += 256) {
            int t = c >> 10, idx = c & 1023, row = idx >> 3, cg = idx & 7;
            const __hip_bfloat16* src = t ? (Bw + (size_t)(n0 + row) * ldb + (k0 + cg * 8))
                                          : (A  + (size_t)(m0 + row) * lda + (k0 + cg * 8));
            float4 v = *(const float4*)src;
            *(float4*)(smem + t * 16384 + swz128(row, cg * 16)) = v;
        }
        __syncthreads();
#pragma unroll
        for (int ks = 0; ks < 2; ++ks) {
            bf16x8 af[4], bfr[4];
#pragma unroll
            for (int m = 0; m < 4; ++m)
                af[m] = *(const bf16x8*)(smem + swz128(wr * 64 + m * 16 + lo, ks * 64 + hi * 16));
#pragma unroll
            for (int n = 0; n < 4; ++n)
                bfr[n] = *(const bf16x8*)(smem + 16384 + swz128(wc * 64 + n * 16 + lo, ks * 64 + hi * 16));
#pragma unroll
            for (int m = 0; m < 4; ++m)
#pragma unroll
                for (int n = 0; n < 4; ++n)
                    acc[m][n] = __builtin_amdgcn_mfma_f32_16x16x32_bf16(af[m], bfr[n], acc[m][n], 0, 0, 0);
        }
        __syncthreads();
    }

#pragma unroll
    for (int n = 0; n < 4; ++n) {
        int gc = n0 + wc * 64 + n * 16 + lo;
        float bz = bias[gc];
#pragma unroll
        for (int m = 0; m < 4; ++m) {
            int gr = m0 + wr * 64 + m * 16 + hi * 4;
#pragma unroll
            for (int r = 0; r < 4; ++r) {
                float v = acc[m][n][r] + bz;
                size_t o = (size_t)(gr + r) * ldc + gc;
                if (Cf) Cf[o] = v;
                if (Cb) *(ushort*)(Cb + o) = bf16_rne(v);
            }
        }
    }
}

// ---------------- V part of QKV -> Vt[B,H,HD,S], scaled by softmax(aw)[h] ----------------
__global__ __launch_bounds__(256) void transpose_v_kernel(const __hip_bfloat16* __restrict__ QKV,
                                                          __hip_bfloat16* __restrict__ Vt,
                                                          const float* __restrict__ aw) {
    __shared__ __align__(16) ushort tile[64][80];
    const int tid = threadIdx.x;
    const int nt = S_ / 64;
    const int blk = blockIdx.x;
    const int t0 = (blk % nt) * 64;
    const int bh = blk / nt;
    const int h = bh % H_, b = bh / H_;

    float mx = aw[0];
    for (int i = 1; i < H_; ++i) mx = fmaxf(mx, aw[i]);
    float sm = 0.f;
    for (int i = 0; i < H_; ++i) sm += expf(aw[i] - mx);
    const float hw = expf(aw[h] - mx) / sm;

#pragma unroll
    for (int c = tid; c < 512; c += 256) {
        int row = c >> 3, cg = c & 7;
        float4 v = *(const float4*)(QKV + (size_t)(b * S_ + t0 + row) * QKVLD + 2 * DM_ + h * HD_ + cg * 8);
        *(float4*)(&tile[row][cg * 8]) = v;
    }
    __syncthreads();
#pragma unroll
    for (int c = tid; c < 512; c += 256) {
        int d = c >> 3, tg = c & 7;
        union { ushort u[8]; float4 v; } tmp;
#pragma unroll
        for (int j = 0; j < 8; ++j) {
            uint bits = (uint)tile[tg * 8 + j][d] << 16;
            float f = __builtin_bit_cast(float, bits) * hw;
            tmp.u[j] = bf16_rne(f);
        }
        *(float4*)(Vt + ((size_t)(b * H_ + h) * HD_ + d) * S_ + t0 + tg * 8) = tmp.v;
    }
}

// ---------------- fused attention: ctx = gelu(Q K^T) @ (V*hw) ----------------
__global__ __launch_bounds__(256, 2) void attn_kernel(
    const __hip_bfloat16* __restrict__ QKV, const __hip_bfloat16* __restrict__ Vt,
    __hip_bfloat16* __restrict__ ctx)
{
    __shared__ __align__(16) char k_lds[8192];
    __shared__ __align__(16) char v_lds[8192];
    __shared__ __align__(16) char p_lds[4][2048];

    const int tid = threadIdx.x;
    const int w = tid >> 6, lane = tid & 63, hi = lane >> 4, lo = lane & 15;
    const int nq = S_ / 64;
    const int blk = blockIdx.x;
    const int q0 = (blk % nq) * 64;
    const int bh = blk / nq;
    const int h = bh % H_, b = bh / H_;

    // Q fragments (scale pre-folded into Wq/bq)
    bf16x8 aq[2];
    {
        const __hip_bfloat16* qrow = QKV + ((size_t)(b * S_ + q0 + w * 16 + lo) * QKVLD + h * HD_);
        aq[0] = *(const bf16x8*)(qrow + hi * 8);
        aq[1] = *(const bf16x8*)(qrow + 32 + hi * 8);
    }

    // hoisted staging addresses: each thread stages rows (ra, ra+32) of K and V tiles
    const int ra = tid >> 3, cg = tid & 7;
    const int dst0 = swz128(ra, cg * 16), dst1 = swz128(ra + 32, cg * 16);
    const __hip_bfloat16* ksrc = QKV + (size_t)(b * S_ + ra) * QKVLD + DM_ + h * HD_ + cg * 8;
    const __hip_bfloat16* vsrc = Vt + ((size_t)(b * H_ + h) * HD_ + ra) * S_ + cg * 8;

    // hoisted fragment addresses
    int fragaddr[2][4], paddr[4][4], praddr[2];
#pragma unroll
    for (int ks = 0; ks < 2; ++ks) {
        praddr[ks] = swz128(lo, ks * 64 + hi * 16);
#pragma unroll
        for (int n = 0; n < 4; ++n)
            fragaddr[ks][n] = swz128(n * 16 + lo, ks * 64 + hi * 16);
    }
#pragma unroll
    for (int n = 0; n < 4; ++n)
#pragma unroll
        for (int r = 0; r < 4; ++r)
            paddr[n][r] = swz128(hi * 4 + r, (n * 16 + lo) * 2);

    f32x4 cacc[4];
#pragma unroll
    for (int n = 0; n < 4; ++n) cacc[n] = (f32x4){0.f, 0.f, 0.f, 0.f};

    for (int t = 0; t < S_ / 64; ++t) {
        *(float4*)(k_lds + dst0) = *(const float4*)(ksrc);
        *(float4*)(k_lds + dst1) = *(const float4*)(ksrc + (size_t)32 * QKVLD);
        *(float4*)(v_lds + dst0) = *(const float4*)(vsrc);
        *(float4*)(v_lds + dst1) = *(const float4*)(vsrc + 32 * S_);
        __syncthreads();

        f32x4 sacc[4];
#pragma unroll
        for (int n = 0; n < 4; ++n) sacc[n] = (f32x4){0.f, 0.f, 0.f, 0.f};
#pragma unroll
        for (int ks = 0; ks < 2; ++ks)
#pragma unroll
            for (int n = 0; n < 4; ++n) {
                bf16x8 bk = *(const bf16x8*)(k_lds + fragaddr[ks][n]);
                sacc[n] = __builtin_amdgcn_mfma_f32_16x16x32_bf16(aq[ks], bk, sacc[n], 0, 0, 0);
            }
#pragma unroll
        for (int n = 0; n < 4; ++n)
#pragma unroll
            for (int r = 0; r < 4; ++r)
                *(ushort*)(p_lds[w] + paddr[n][r]) = bf16_rne(gelu_fast(sacc[n][r]));
#pragma unroll
        for (int ks = 0; ks < 2; ++ks) {
            bf16x8 pa = *(const bf16x8*)(p_lds[w] + praddr[ks]);
#pragma unroll
            for (int n = 0; n < 4; ++n) {
                bf16x8 bv = *(const bf16x8*)(v_lds + fragaddr[ks][n]);
                cacc[n] = __builtin_amdgcn_mfma_f32_16x16x32_bf16(pa, bv, cacc[n], 0, 0, 0);
            }
        }
        __syncthreads();
        ksrc += (size_t)64 * QKVLD;
        vsrc += 64;
    }

#pragma unroll
    for (int n = 0; n < 4; ++n)
#pragma unroll
        for (int r = 0; r < 4; ++r) {
            int srow = q0 + w * 16 + hi * 4 + r;
            int d = n * 16 + lo;
            *(ushort*)(ctx + (size_t)(b * S_ + srow) * DM_ + h * HD_ + d) = bf16_rne(cacc[n][r]);
        }
}

// ---------------- gate mix + residual + LayerNorm ----------------
__global__ __launch_bounds__(256) void epilogue_ln_kernel(
    const float* __restrict__ outp, const float* __restrict__ gpre,
    const float* __restrict__ x, const float* __restrict__ gamma,
    const float* __restrict__ beta, float* __restrict__ y)
{
    const int row = blockIdx.x, tid = threadIdx.x;
    const size_t base = (size_t)row * DM_ + tid * 4;
    float4 ov = *(const float4*)(outp + base);
    float4 gv = *(const float4*)(gpre + base);
    float4 xv = *(const float4*)(x + base);
    float yv[4];
    float s = 0.f, s2 = 0.f;
#pragma unroll
    for (int j = 0; j < 4; ++j) {
        float o = ((float*)&ov)[j], g = ((float*)&gv)[j], xx = ((float*)&xv)[j];
        float gate = __builtin_amdgcn_rcpf(1.f + __expf(-g));
        float yy = gate * o + (1.f - gate) * xx + xx;
        yv[j] = yy;
        s += yy; s2 += yy * yy;
    }
    const int w = tid >> 6, lane = tid & 63;
#pragma unroll
    for (int off = 32; off > 0; off >>= 1) {
        s  += __shfl_down(s, off, 64);
        s2 += __shfl_down(s2, off, 64);
    }
    __shared__ float red[8];
    if (lane == 0) { red[w] = s; red[4 + w] = s2; }
    __syncthreads();
    s  = red[0] + red[1] + red[2] + red[3];
    s2 = red[4] + red[5] + red[6] + red[7];
    const float mu = s * (1.f / DM_);
    const float var = s2 * (1.f / DM_) - mu * mu;
    const float rstd = rsqrtf(var + 1e-5f);
    float4 outv;
#pragma unroll
    for (int j = 0; j < 4; ++j) {
        int col = tid * 4 + j;
        ((float*)&outv)[j] = (yv[j] - mu) * rstd * gamma[col] + beta[col];
    }
    *(float4*)(y + base) = outv;
}

extern "C" void kernel_launch(void* const* d_in, const int* in_sizes, int n_in,
                              void* d_out, int out_size, void* d_ws, size_t ws_size,
                              hipStream_t stream) {
    const float* x  = (const float*)d_in[0];
    const float* Wq = (const float*)d_in[1];
    const float* bq = (const float*)d_in[2];
    const float* Wk = (const float*)d_in[3];
    const float* bk = (const float*)d_in[4];
    const float* Wv = (const float*)d_in[5];
    const float* bv = (const float*)d_in[6];
    const float* Wo = (const float*)d_in[7];
    const float* bo = (const float*)d_in[8];
    const float* Wg = (const float*)d_in[9];
    const float* bg = (const float*)d_in[10];
    const float* aw = (const float*)d_in[11];
    const float* gamma = (const float*)d_in[12];
    const float* beta  = (const float*)d_in[13];

    char* ws = (char*)d_ws;
    size_t off = 0;
    auto alloc = [&](size_t bytes) -> char* {
        char* p = ws + off;
        off += (bytes + 255) & ~(size_t)255;
        return p;
    };
    const size_t NTOK = (size_t)B_ * S_;   // 4096
    const size_t NELT = NTOK * DM_;        // 4194304
    const size_t WELT = (size_t)DM_ * DM_;

    __hip_bfloat16* xb    = (__hip_bfloat16*)alloc(NELT * 2);
    __hip_bfloat16* Wqkvb = (__hip_bfloat16*)alloc(3 * WELT * 2);
    __hip_bfloat16* Wob   = (__hip_bfloat16*)alloc(WELT * 2);
    __hip_bfloat16* Wgb   = (__hip_bfloat16*)alloc(WELT * 2);
    float*          bqkv  = (float*)alloc(3 * DM_ * 4);
    __hip_bfloat16* qkvb  = (__hip_bfloat16*)alloc(NTOK * QKVLD * 2);
    __hip_bfloat16* Vtb   = (__hip_bfloat16*)alloc(NELT * 2);
    __hip_bfloat16* ctxb  = (__hip_bfloat16*)alloc(NELT * 2);
    float*          outf  = (float*)alloc(NELT * 4);
    __hip_bfloat16* outb  = (__hip_bfloat16*)alloc(NELT * 2);
    float*          gpre  = (float*)alloc(NELT * 4);

    // casts (scale folded into Wq; Wq/Wk/Wv concatenated row-wise)
    cast_bf16_kernel<<<(int)(NELT / 1024), 256, 0, stream>>>(x, xb, (int)NELT, 1.0f);
    cast_bf16_kernel<<<1024, 256, 0, stream>>>(Wq, Wqkvb,            (int)WELT, 0.125f);
    cast_bf16_kernel<<<1024, 256, 0, stream>>>(Wk, Wqkvb + WELT,     (int)WELT, 1.0f);
    cast_bf16_kernel<<<1024, 256, 0, stream>>>(Wv, Wqkvb + 2 * WELT, (int)WELT, 1.0f);
    cast_bf16_kernel<<<1024, 256, 0, stream>>>(Wo, Wob, (int)WELT, 1.0f);
    cast_bf16_kernel<<<1024, 256, 0, stream>>>(Wg, Wgb, (int)WELT, 1.0f);
    concat_bias_kernel<<<12, 256, 0, stream>>>(bq, bk, bv, bqkv);

    // fused QKV projection: [4096,1024] x [3072,1024]^T -> [4096,3072]
    gemm_nt_kernel<<<dim3(QKVLD / 128, (int)(NTOK / 128)), 256, 0, stream>>>(
        xb, DM_, Wqkvb, DM_, bqkv, nullptr, qkvb, QKVLD, (int)NTOK, QKVLD, DM_);

    transpose_v_kernel<<<B_ * H_ * (S_ / 64), 256, 0, stream>>>(qkvb, Vtb, aw);
    attn_kernel<<<B_ * H_ * (S_ / 64), 256, 0, stream>>>(qkvb, Vtb, ctxb);

    gemm_nt_kernel<<<dim3(DM_ / 128, (int)(NTOK / 128)), 256, 0, stream>>>(
        ctxb, DM_, Wob, DM_, bo, outf, outb, DM_, (int)NTOK, DM_, DM_);
    gemm_nt_kernel<<<dim3(DM_ / 128, (int)(NTOK / 128)), 256, 0, stream>>>(
        outb, DM_, Wgb, DM_, bg, gpre, nullptr, DM_, (int)NTOK, DM_, DM_);

    epilogue_ln_kernel<<<(int)NTOK, 256, 0, stream>>>(outf, gpre, x, gamma, beta, (float*)d_out);
}

// Round 3
// 175.174 us; speedup vs baseline: 2.1187x; 1.4042x over previous
//
#include <hip/hip_runtime.h>
#include <hip/hip_bf16.h>

#define B_ 2
#define S_ 2048
#define DM_ 1024
#define H_ 16
#define HD_ 64
#define QKVLD 3072
#define WELT_ ((size_t)DM_ * DM_)

using bf16x8 = __attribute__((ext_vector_type(8))) short;
using f32x4  = __attribute__((ext_vector_type(4))) float;
using f32x16 = __attribute__((ext_vector_type(16))) float;

// async global->LDS, 16B per lane, wave-uniform LDS base
#define GLOAD16(g, l) __builtin_amdgcn_global_load_lds( \
    (const __attribute__((address_space(1))) void*)(g), \
    (__attribute__((address_space(3))) void*)(l), 16, 0, 0)

// XOR swizzle for [*][64]-bf16 tiles (128B row stride). LDS slot col16 holds
// logical col col16^(row&7); read for logical col c at slot c^(row&7).
__device__ __forceinline__ int swz128(int row, int bytecol) {
    return row * 128 + (bytecol ^ ((row & 7) << 4));
}

// tanh-form GELU; max err vs exact-erf ~2e-4.
__device__ __forceinline__ float gelu_fast(float x) {
    float t = x * fmaf(x * x, 0.1029451f, 2.3022082f);
    float e = __builtin_amdgcn_exp2f(t);
    float r = __builtin_amdgcn_rcpf(e + 1.0f);
    return x * (1.0f - r);
}

__device__ __forceinline__ ushort bf16_rne(float f) {
    uint b = __builtin_bit_cast(uint, f);
    b += 0x7FFF + ((b >> 16) & 1);
    return (ushort)(b >> 16);
}

__device__ __forceinline__ uint cvtpk(float lo, float hi) {
    uint r;
    asm("v_cvt_pk_bf16_f32 %0, %1, %2" : "=v"(r) : "v"(lo), "v"(hi));
    return r;
}
// new_a = {a.lo, b.lo}; new_b = {a.hi, b.hi}
__device__ __forceinline__ void pl32swap(uint& a, uint& b) {
    asm volatile("v_permlane32_swap_b32 %0, %1" : "+v"(a), "+v"(b));
}

// ---------------- x cast ----------------
__global__ __launch_bounds__(256) void cast_bf16_kernel(const float* __restrict__ in,
                                                        __hip_bfloat16* __restrict__ out, int n) {
    int i = (blockIdx.x * 256 + threadIdx.x) * 4;
    if (i >= n) return;
    float4 v = *(const float4*)(in + i);
    ushort4 o = { bf16_rne(v.x), bf16_rne(v.y), bf16_rne(v.z), bf16_rne(v.w) };
    *(ushort4*)(out + i) = o;
}

// ---------------- fused weight casts (q*0.125,k,v,o,g) + bias concat ----------------
__global__ __launch_bounds__(256) void prep_kernel(
    const float* __restrict__ Wq, const float* __restrict__ Wk, const float* __restrict__ Wv,
    const float* __restrict__ Wo, const float* __restrict__ Wg,
    const float* __restrict__ bq, const float* __restrict__ bk, const float* __restrict__ bv,
    __hip_bfloat16* __restrict__ Wdst, float* __restrict__ bqkv)
{
    int blk = blockIdx.x;
    if (blk < 5120) {
        int widx = blk >> 10;
        int off = (blk & 1023) * 1024 + threadIdx.x * 4;
        const float* src = widx == 0 ? Wq : widx == 1 ? Wk : widx == 2 ? Wv : widx == 3 ? Wo : Wg;
        float scale = widx == 0 ? 0.125f : 1.0f;
        float4 v = *(const float4*)(src + off);
        ushort4 o = { bf16_rne(v.x * scale), bf16_rne(v.y * scale),
                      bf16_rne(v.z * scale), bf16_rne(v.w * scale) };
        *(ushort4*)(Wdst + widx * WELT_ + off) = o;
    } else {
        int i = (blk - 5120) * 256 + threadIdx.x;
        if (i < 3 * DM_) {
            float v = (i < DM_) ? bq[i] * 0.125f : (i < 2 * DM_ ? bk[i - DM_] : bv[i - 2 * DM_]);
            bqkv[i] = v;
        }
    }
}

// ---------------- NT bf16 GEMM: C = A * Bw^T + bias (global_load_lds staging) ----------------
__global__ __launch_bounds__(256, 2) void gemm_nt_kernel(
    const __hip_bfloat16* __restrict__ A, int lda,
    const __hip_bfloat16* __restrict__ Bw, int ldb,
    const float* __restrict__ bias, float* __restrict__ Cf,
    __hip_bfloat16* __restrict__ Cb, int ldc, int M, int N, int K)
{
    __shared__ __align__(16) char smem[32768];
    const int tid = threadIdx.x;
    const int w = tid >> 6, lane = tid & 63, hi = lane >> 4, lo = lane & 15;
    const int wr = w >> 1, wc = w & 1;
    const int m0 = blockIdx.y * 128, n0 = blockIdx.x * 128;

    // staging: waves 0,1 -> A rows w*64+.., waves 2,3 -> B. 8 x 1KB instr per wave.
    // linear LDS (row,col16); source col pre-swizzled: scol = (lane&7) ^ (row&7)
    const int srow = lane >> 3;                 // 0..7
    const int scol = (lane & 7) ^ srow;
    const __hip_bfloat16* sbase;
    int sld;
    char* lbase;
    if (w < 2) {
        sbase = A + (size_t)(m0 + w * 64 + srow) * lda + scol * 8;
        sld = lda;
        lbase = smem + w * 8192;
    } else {
        sbase = Bw + (size_t)(n0 + (w - 2) * 64 + srow) * ldb + scol * 8;
        sld = ldb;
        lbase = smem + 16384 + (w - 2) * 8192;
    }

    f32x4 acc[4][4];
#pragma unroll
    for (int m = 0; m < 4; ++m)
#pragma unroll
        for (int n = 0; n < 4; ++n) acc[m][n] = (f32x4){0.f, 0.f, 0.f, 0.f};

    for (int k0 = 0; k0 < K; k0 += 64) {
#pragma unroll
        for (int i = 0; i < 8; ++i)
            GLOAD16(sbase + (size_t)i * 8 * sld + k0, lbase + i * 1024);
        __syncthreads();
#pragma unroll
        for (int ks = 0; ks < 2; ++ks) {
            bf16x8 af[4], bfr[4];
#pragma unroll
            for (int m = 0; m < 4; ++m)
                af[m] = *(const bf16x8*)(smem + swz128(wr * 64 + m * 16 + lo, ks * 64 + hi * 16));
#pragma unroll
            for (int n = 0; n < 4; ++n)
                bfr[n] = *(const bf16x8*)(smem + 16384 + swz128(wc * 64 + n * 16 + lo, ks * 64 + hi * 16));
#pragma unroll
            for (int m = 0; m < 4; ++m)
#pragma unroll
                for (int n = 0; n < 4; ++n)
                    acc[m][n] = __builtin_amdgcn_mfma_f32_16x16x32_bf16(af[m], bfr[n], acc[m][n], 0, 0, 0);
        }
        __syncthreads();
    }

#pragma unroll
    for (int n = 0; n < 4; ++n) {
        int gc = n0 + wc * 64 + n * 16 + lo;
        float bz = bias[gc];
#pragma unroll
        for (int m = 0; m < 4; ++m) {
            int gr = m0 + wr * 64 + m * 16 + hi * 4;
#pragma unroll
            for (int r = 0; r < 4; ++r) {
                float v = acc[m][n][r] + bz;
                size_t o = (size_t)(gr + r) * ldc + gc;
                if (Cf) Cf[o] = v;
                if (Cb) *(ushort*)(Cb + o) = bf16_rne(v);
            }
        }
    }
}

// ---------------- V slice of QKV -> Vt[B,H,HD,S], scaled by softmax(aw)[h] ----------------
__global__ __launch_bounds__(256) void transpose_v_kernel(const __hip_bfloat16* __restrict__ QKV,
                                                          __hip_bfloat16* __restrict__ Vt,
                                                          const float* __restrict__ aw) {
    __shared__ __align__(16) ushort tile[64][80];
    const int tid = threadIdx.x;
    const int nt = S_ / 64;
    const int blk = blockIdx.x;
    const int t0 = (blk % nt) * 64;
    const int bh = blk / nt;
    const int h = bh % H_, b = bh / H_;

    float mx = aw[0];
    for (int i = 1; i < H_; ++i) mx = fmaxf(mx, aw[i]);
    float sm = 0.f;
    for (int i = 0; i < H_; ++i) sm += expf(aw[i] - mx);
    const float hw = expf(aw[h] - mx) / sm;

#pragma unroll
    for (int c = tid; c < 512; c += 256) {
        int row = c >> 3, cg = c & 7;
        float4 v = *(const float4*)(QKV + (size_t)(b * S_ + t0 + row) * QKVLD + 2 * DM_ + h * HD_ + cg * 8);
        *(float4*)(&tile[row][cg * 8]) = v;
    }
    __syncthreads();
#pragma unroll
    for (int c = tid; c < 512; c += 256) {
        int d = c >> 3, tg = c & 7;
        union { ushort u[8]; float4 v; } tmp;
#pragma unroll
        for (int j = 0; j < 8; ++j) {
            uint bits = (uint)tile[tg * 8 + j][d] << 16;
            tmp.u[j] = bf16_rne(__builtin_bit_cast(float, bits) * hw);
        }
        *(float4*)(Vt + ((size_t)(b * H_ + h) * HD_ + d) * S_ + t0 + tg * 8) = tmp.v;
    }
}

// ---------------- fused attention, 32x32 MFMA, in-register P ----------------
// block: 4 waves x 32 q-rows = 128 q; K/V tiles of 64 t staged via global_load_lds.
__global__ __launch_bounds__(256, 2) void attn_kernel(
    const __hip_bfloat16* __restrict__ QKV, const __hip_bfloat16* __restrict__ Vt,
    __hip_bfloat16* __restrict__ ctx)
{
    __shared__ __align__(16) char k_lds[8192];   // K tile: 64 t x 64 d
    __shared__ __align__(16) char v_lds[8192];   // Vt tile: 64 d x 64 t

    const int tid = threadIdx.x;
    const int w = tid >> 6, lane = tid & 63;
    const int l31 = lane & 31, hi2 = lane >> 5;
    const int nq = S_ / 128;                     // 16
    const int blk = blockIdx.x;
    const int q0 = (blk % nq) * 128;
    const int bh = blk / nq;
    const int h = bh % H_, b = bh / H_;

    // Q fragments (B-operand): qf[ks] = Q[q0+w*32+l31][ks*16 + hi2*8 .. +8)
    bf16x8 qf[4];
    {
        const __hip_bfloat16* qrow = QKV + ((size_t)(b * S_ + q0 + w * 32 + l31) * QKVLD + h * HD_);
#pragma unroll
        for (int ks = 0; ks < 4; ++ks)
            qf[ks] = *(const bf16x8*)(qrow + ks * 16 + hi2 * 8);
    }

    // staging: wave w stages K rows [w*16,+16) and Vt rows [w*16,+16), 2 x 1KB each
    const int srow = lane >> 3;                  // 0..7
    const int scol = (lane & 7) ^ srow;
    const __hip_bfloat16* kptr = QKV + (size_t)(b * S_ + w * 16 + srow) * QKVLD + DM_ + h * HD_ + scol * 8;
    const __hip_bfloat16* vptr = Vt + ((size_t)(b * H_ + h) * HD_ + w * 16 + srow) * S_ + scol * 8;
    char* klds_w = k_lds + w * 2048;
    char* vlds_w = v_lds + w * 2048;

    f32x16 cacc[2];
#pragma unroll
    for (int n = 0; n < 2; ++n)
#pragma unroll
        for (int r = 0; r < 16; ++r) cacc[n][r] = 0.f;

    for (int t = 0; t < S_ / 64; ++t) {
        GLOAD16(kptr, klds_w);
        GLOAD16(kptr + (size_t)8 * QKVLD, klds_w + 1024);
        GLOAD16(vptr, vlds_w);
        GLOAD16(vptr + 8 * S_, vlds_w + 1024);
        __syncthreads();

        // S^T tile: sacc[n] = K-chunk(n) . Q  -> D[col=l31=q][row=t']
#pragma unroll
        for (int n = 0; n < 2; ++n) {
            f32x16 sacc;
#pragma unroll
            for (int r = 0; r < 16; ++r) sacc[r] = 0.f;
#pragma unroll
            for (int ks = 0; ks < 4; ++ks) {
                bf16x8 kf = *(const bf16x8*)(k_lds + swz128(n * 32 + l31, ks * 32 + hi2 * 16));
                sacc = __builtin_amdgcn_mfma_f32_32x32x16_bf16(kf, qf[ks], sacc, 0, 0, 0);
            }
            // GELU in registers
            float p[16];
#pragma unroll
            for (int r = 0; r < 16; ++r) p[r] = gelu_fast(sacc[r]);
            // pack to bf16 pairs + permlane32_swap -> PV A-frags (T12 recipe)
            uint a0 = cvtpk(p[0], p[1]),  b0 = cvtpk(p[4], p[5]);
            uint a1 = cvtpk(p[2], p[3]),  b1 = cvtpk(p[6], p[7]);
            uint a2 = cvtpk(p[8], p[9]),  b2 = cvtpk(p[12], p[13]);
            uint a3 = cvtpk(p[10], p[11]), b3 = cvtpk(p[14], p[15]);
            pl32swap(a0, b0); pl32swap(a1, b1); pl32swap(a2, b2); pl32swap(a3, b3);
            union { uint u[4]; bf16x8 v; } pa0, pa1;
            pa0.u[0] = a0; pa0.u[1] = a1; pa0.u[2] = b0; pa0.u[3] = b1;
            pa1.u[0] = a2; pa1.u[1] = a3; pa1.u[2] = b2; pa1.u[3] = b3;
            // PV: kc = n*2 + kc2 (t-chunks of 16)
#pragma unroll
            for (int kc2 = 0; kc2 < 2; ++kc2) {
                int kc = n * 2 + kc2;
                bf16x8 pa = kc2 ? pa1.v : pa0.v;
#pragma unroll
                for (int n2 = 0; n2 < 2; ++n2) {
                    bf16x8 vf = *(const bf16x8*)(v_lds + swz128(n2 * 32 + l31, kc * 32 + hi2 * 16));
                    cacc[n2] = __builtin_amdgcn_mfma_f32_32x32x16_bf16(pa, vf, cacc[n2], 0, 0, 0);
                }
            }
        }
        __syncthreads();
        kptr += (size_t)64 * QKVLD;
        vptr += 64;
    }

    // C/D 32x32: row=(r&3)+8*(r>>2)+4*hi2 (q-local), col=l31 (d within n2*32)
#pragma unroll
    for (int n2 = 0; n2 < 2; ++n2)
#pragma unroll
        for (int r = 0; r < 16; ++r) {
            int qrow = (r & 3) + 8 * (r >> 2) + 4 * hi2;
            size_t o = (size_t)(b * S_ + q0 + w * 32 + qrow) * DM_ + h * HD_ + n2 * 32 + l31;
            *(ushort*)(ctx + o) = bf16_rne(cacc[n2][r]);
        }
}

// ---------------- gate mix + residual + LayerNorm ----------------
__global__ __launch_bounds__(256) void epilogue_ln_kernel(
    const float* __restrict__ outp, const float* __restrict__ gpre,
    const float* __restrict__ x, const float* __restrict__ gamma,
    const float* __restrict__ beta, float* __restrict__ y)
{
    const int row = blockIdx.x, tid = threadIdx.x;
    const size_t base = (size_t)row * DM_ + tid * 4;
    float4 ov = *(const float4*)(outp + base);
    float4 gv = *(const float4*)(gpre + base);
    float4 xv = *(const float4*)(x + base);
    float yv[4];
    float s = 0.f, s2 = 0.f;
#pragma unroll
    for (int j = 0; j < 4; ++j) {
        float o = ((float*)&ov)[j], g = ((float*)&gv)[j], xx = ((float*)&xv)[j];
        float gate = __builtin_amdgcn_rcpf(1.f + __expf(-g));
        float yy = gate * o + (1.f - gate) * xx + xx;
        yv[j] = yy;
        s += yy; s2 += yy * yy;
    }
    const int w = tid >> 6, lane = tid & 63;
#pragma unroll
    for (int off = 32; off > 0; off >>= 1) {
        s  += __shfl_down(s, off, 64);
        s2 += __shfl_down(s2, off, 64);
    }
    __shared__ float red[8];
    if (lane == 0) { red[w] = s; red[4 + w] = s2; }
    __syncthreads();
    s  = red[0] + red[1] + red[2] + red[3];
    s2 = red[4] + red[5] + red[6] + red[7];
    const float mu = s * (1.f / DM_);
    const float var = s2 * (1.f / DM_) - mu * mu;
    const float rstd = rsqrtf(var + 1e-5f);
    float4 outv;
#pragma unroll
    for (int j = 0; j < 4; ++j) {
        int col = tid * 4 + j;
        ((float*)&outv)[j] = (yv[j] - mu) * rstd * gamma[col] + beta[col];
    }
    *(float4*)(y + base) = outv;
}

extern "C" void kernel_launch(void* const* d_in, const int* in_sizes, int n_in,
                              void* d_out, int out_size, void* d_ws, size_t ws_size,
                              hipStream_t stream) {
    const float* x  = (const float*)d_in[0];
    const float* Wq = (const float*)d_in[1];
    const float* bq = (const float*)d_in[2];
    const float* Wk = (const float*)d_in[3];
    const float* bk = (const float*)d_in[4];
    const float* Wv = (const float*)d_in[5];
    const float* bv = (const float*)d_in[6];
    const float* Wo = (const float*)d_in[7];
    const float* bo = (const float*)d_in[8];
    const float* Wg = (const float*)d_in[9];
    const float* bg = (const float*)d_in[10];
    const float* aw = (const float*)d_in[11];
    const float* gamma = (const float*)d_in[12];
    const float* beta  = (const float*)d_in[13];

    char* ws = (char*)d_ws;
    size_t off = 0;
    auto alloc = [&](size_t bytes) -> char* {
        char* p = ws + off;
        off += (bytes + 255) & ~(size_t)255;
        return p;
    };
    const size_t NTOK = (size_t)B_ * S_;   // 4096
    const size_t NELT = NTOK * DM_;        // 4194304

    __hip_bfloat16* xb    = (__hip_bfloat16*)alloc(NELT * 2);
    __hip_bfloat16* Wall  = (__hip_bfloat16*)alloc(5 * WELT_ * 2);  // q,k,v,o,g contiguous
    float*          bqkv  = (float*)alloc(3 * DM_ * 4);
    __hip_bfloat16* qkvb  = (__hip_bfloat16*)alloc(NTOK * QKVLD * 2);
    __hip_bfloat16* Vtb   = (__hip_bfloat16*)alloc(NELT * 2);
    __hip_bfloat16* ctxb  = (__hip_bfloat16*)alloc(NELT * 2);
    float*          outf  = (float*)alloc(NELT * 4);
    __hip_bfloat16* outb  = (__hip_bfloat16*)alloc(NELT * 2);
    float*          gpre  = (float*)alloc(NELT * 4);

    cast_bf16_kernel<<<(int)(NELT / 1024), 256, 0, stream>>>(x, xb, (int)NELT);
    prep_kernel<<<5120 + 12, 256, 0, stream>>>(Wq, Wk, Wv, Wo, Wg, bq, bk, bv, Wall, bqkv);

    // fused QKV projection: [4096,1024] x [3072,1024]^T
    gemm_nt_kernel<<<dim3(QKVLD / 128, (int)(NTOK / 128)), 256, 0, stream>>>(
        xb, DM_, Wall, DM_, bqkv, nullptr, qkvb, QKVLD, (int)NTOK, QKVLD, DM_);

    transpose_v_kernel<<<B_ * H_ * (S_ / 64), 256, 0, stream>>>(qkvb, Vtb, aw);
    attn_kernel<<<B_ * H_ * (S_ / 128), 256, 0, stream>>>(qkvb, Vtb, ctxb);

    gemm_nt_kernel<<<dim3(DM_ / 128, (int)(NTOK / 128)), 256, 0, stream>>>(
        ctxb, DM_, Wall + 3 * WELT_, DM_, bo, outf, outb, DM_, (int)NTOK, DM_, DM_);
    gemm_nt_kernel<<<dim3(DM_ / 128, (int)(NTOK / 128)), 256, 0, stream>>>(
        outb, DM_, Wall + 4 * WELT_, DM_, bg, gpre, nullptr, DM_, (int)NTOK, DM_, DM_);

    epilogue_ln_kernel<<<(int)NTOK, 256, 0, stream>>>(outf, gpre, x, gamma, beta, (float*)d_out);
}